// Round 4
// baseline (315.130 us; speedup 1.0000x reference)
//
#include <hip/hip_runtime.h>
#include <hip/hip_bf16.h>

#define BB 16

typedef __attribute__((ext_vector_type(8))) short bf16x8;
typedef __attribute__((ext_vector_type(4))) float f32x4;

__device__ __forceinline__ unsigned short f2bfbits(float f) {
    union { float f; unsigned u; } v; v.f = f;
    unsigned r = v.u + 0x7fffu + ((v.u >> 16) & 1u);   // RNE
    return (unsigned short)(r >> 16);
}
__device__ __forceinline__ float bfraw(unsigned short u) {
    union { unsigned u; float f; } v; v.u = ((unsigned)u) << 16; return v.f;
}
__device__ __forceinline__ unsigned packbf2(float lo, float hi) {
    return (unsigned)f2bfbits(lo) | ((unsigned)f2bfbits(hi) << 16);
}

// ---------------------------------------------------------------------------
// prep: fp32 params -> bf16 ws copies. w_all=[theta;phi;g] [192][256],
// w_o_bf [256][128], b_all fp32 [192].
// ---------------------------------------------------------------------------
__global__ void prep_kernel(
    const float* __restrict__ wt, const float* __restrict__ bt,
    const float* __restrict__ wp, const float* __restrict__ bp,
    const float* __restrict__ wg, const float* __restrict__ bg,
    const float* __restrict__ wo,
    unsigned short* __restrict__ w_all, unsigned short* __restrict__ w_o_bf,
    float* __restrict__ b_all)
{
    int i = blockIdx.x * 256 + threadIdx.x;
    if (i < 8192)        w_all[i] = f2bfbits(wt[i]);
    else if (i < 16384)  w_all[i] = f2bfbits(wp[i - 8192]);
    else if (i < 49152)  w_all[i] = f2bfbits(wg[i - 16384]);
    else if (i < 81920)  w_o_bf[i - 49152] = f2bfbits(wo[i - 49152]);
    else if (i < 82112) {
        int r = i - 81920;
        b_all[r] = (r < 32) ? bt[r] : (r < 64) ? bp[r - 32] : bg[r - 64];
    }
}

// ---------------------------------------------------------------------------
// xT: x fp32 [B][256][4096] -> x_t bf16 [B][4096][256]. 64x64 LDS tiles.
// ---------------------------------------------------------------------------
__global__ __launch_bounds__(256) void xt_kernel(
    const float* __restrict__ x, unsigned short* __restrict__ x_t)
{
    __shared__ unsigned short lt[64 * 74];   // [c][p] pad 74 (37 dw, gcd(5,32)=1)

    const int t = threadIdx.x;
    const int bid = blockIdx.x;
    const int b  = bid >> 8;
    const int p0 = ((bid >> 2) & 63) << 6;
    const int c0 = (bid & 3) << 6;

    {
        int c = t & 63, seg = t >> 6;
        const float* src = x + ((size_t)(b * 256 + c0 + c)) * 4096 + p0 + seg * 16;
        #pragma unroll
        for (int j = 0; j < 4; ++j) {
            float4 v = *(const float4*)(src + 4 * j);
            unsigned* dst = (unsigned*)(lt + c * 74 + seg * 16 + 4 * j);
            dst[0] = packbf2(v.x, v.y);
            dst[1] = packbf2(v.z, v.w);
        }
    }
    __syncthreads();
    {
        int p = t >> 2, quad = t & 3;
        #pragma unroll
        for (int h = 0; h < 2; ++h) {
            union { unsigned short u[8]; int4 v; } o;
            #pragma unroll
            for (int e = 0; e < 8; ++e)
                o.u[e] = lt[(quad * 16 + h * 8 + e) * 74 + p];
            *(int4*)(x_t + ((size_t)(b * 4096 + p0 + p)) * 256 + c0 + quad * 16 + h * 8) = o.v;
        }
    }
}

// ---------------------------------------------------------------------------
// proj: [192 co] x [256 cin] x [128 pos/block], A=w_all, B=x_t (both int4),
// + bias, theta transpose-out, 2x2 maxpool for phi/g.
// ---------------------------------------------------------------------------
__global__ __launch_bounds__(256, 2) void proj_kernel(
    const unsigned short* __restrict__ x_t,
    const unsigned short* __restrict__ w_all,
    const float* __restrict__ b_all,
    unsigned short* __restrict__ theta_t,   // [B][4096][32]
    unsigned short* __restrict__ phi_t,     // [B][1024][32]
    unsigned short* __restrict__ g)         // [B][128][1024]
{
    __shared__ unsigned short ot[192 * 136];   // [co][pos] pad 136

    const int t = threadIdx.x;
    const int w = t >> 6;
    const int l = t & 63;
    const int lr = l & 15, lg = l >> 4;
    const int b  = blockIdx.x >> 5;
    const int pt = blockIdx.x & 31;
    const int pbase = pt << 7;
    const int mb = pt << 5;

    f32x4 acc[3][8];
    #pragma unroll
    for (int i = 0; i < 3; ++i)
        #pragma unroll
        for (int nt = 0; nt < 8; ++nt) acc[i][nt] = (f32x4){0.f,0.f,0.f,0.f};

    #pragma unroll 1
    for (int ks = 0; ks < 8; ++ks) {
        bf16x8 af[3];
        #pragma unroll
        for (int i = 0; i < 3; ++i)
            af[i] = *(const bf16x8*)(w_all + (size_t)(16*(3*w+i) + lr)*256 + 32*ks + 8*lg);
        #pragma unroll
        for (int nt = 0; nt < 8; ++nt) {
            bf16x8 bx = *(const bf16x8*)(x_t + ((size_t)(b*4096 + pbase + 16*nt + lr))*256 + 32*ks + 8*lg);
            #pragma unroll
            for (int i = 0; i < 3; ++i)
                acc[i][nt] = __builtin_amdgcn_mfma_f32_16x16x32_bf16(af[i], bx, acc[i][nt], 0, 0, 0);
        }
    }

    float bias[3][4];
    #pragma unroll
    for (int i = 0; i < 3; ++i)
        #pragma unroll
        for (int r = 0; r < 4; ++r) bias[i][r] = b_all[16*(3*w+i) + 4*lg + r];
    #pragma unroll
    for (int i = 0; i < 3; ++i)
        #pragma unroll
        for (int nt = 0; nt < 8; ++nt)
            #pragma unroll
            for (int r = 0; r < 4; ++r)
                ot[(16*(3*w+i) + 4*lg + r)*136 + 16*nt + lr] =
                    f2bfbits(acc[i][nt][r] + bias[i][r]);
    __syncthreads();

    // theta rows 0..31 -> theta_t[b][n][32]
    if (t < 128) {
        int p = t;
        union { unsigned short u[32]; int4 v[4]; } th;
        #pragma unroll
        for (int c = 0; c < 32; ++c) th.u[c] = ot[c*136 + p];
        int4* dst = (int4*)(theta_t + ((size_t)(b*4096 + pbase + p)) * 32);
        #pragma unroll
        for (int q = 0; q < 4; ++q) dst[q] = th.v[q];
    }
    // phi pooled (rows 32..63) -> phi_t[b][m][32]
    {
        int ww = t >> 3, c0 = (t & 7) * 4;
        union { unsigned short u[4]; int2 v; } ph;
        #pragma unroll
        for (int e = 0; e < 4; ++e) {
            int row = 32 + c0 + e;
            unsigned p01 = *(const unsigned*)&ot[row*136 + 2*ww];
            unsigned p23 = *(const unsigned*)&ot[row*136 + 64 + 2*ww];
            float m0 = fmaxf(bfraw((unsigned short)p01), bfraw((unsigned short)(p01 >> 16)));
            float m1 = fmaxf(bfraw((unsigned short)p23), bfraw((unsigned short)(p23 >> 16)));
            ph.u[e] = f2bfbits(fmaxf(m0, m1));
        }
        *(int2*)(phi_t + ((size_t)(b*1024 + mb + ww)) * 32 + c0) = ph.v;
    }
    // g pooled (rows 64..191) -> g[b][c2][1024]
    {
        int c2 = t >> 1, w0 = (t & 1) * 16;
        int row = 64 + c2;
        union { unsigned short u[16]; int4 v[2]; } gv;
        #pragma unroll
        for (int e = 0; e < 16; ++e) {
            int ww = w0 + e;
            unsigned p01 = *(const unsigned*)&ot[row*136 + 2*ww];
            unsigned p23 = *(const unsigned*)&ot[row*136 + 64 + 2*ww];
            float m0 = fmaxf(bfraw((unsigned short)p01), bfraw((unsigned short)(p01 >> 16)));
            float m1 = fmaxf(bfraw((unsigned short)p23), bfraw((unsigned short)(p23 >> 16)));
            gv.u[e] = f2bfbits(fmaxf(m0, m1));
        }
        int4* dst = (int4*)(g + ((size_t)(b*128 + c2)) * 1024 + mb + w0);
        dst[0] = gv.v[0]; dst[1] = gv.v[1];
    }
}

// ---------------------------------------------------------------------------
// attn v2: 4 independent waves/block, 16 q per wave, 1024 keys in chunks of 64.
// Swapped QK^T (S^T = phi x theta): lane holds full P-row for q=lane&15.
// ---------------------------------------------------------------------------
__global__ __launch_bounds__(256, 4) void attn_kernel(
    const unsigned short* __restrict__ theta_t,
    const unsigned short* __restrict__ phi_t,
    const unsigned short* __restrict__ g,
    unsigned short* __restrict__ o_pre_t)   // [B][4096][128]
{
    __shared__ unsigned short plds[4][16 * 72];    // per-wave P [q][64m] pad 72
    __shared__ unsigned short olds[4][16 * 136];   // per-wave out stage

    const int t = threadIdx.x;
    const int wv = t >> 6;
    const int l  = t & 63;
    const int lr = l & 15, lg = l >> 4;
    const int b   = blockIdx.x >> 6;
    const int nq0 = (blockIdx.x & 63) * 64 + wv * 16;

    const f32x4 zero = {0.f, 0.f, 0.f, 0.f};

    // theta B-frag: col=q=lr, k contiguous — hoisted
    const bf16x8 aq = *(const bf16x8*)(theta_t + ((size_t)(b*4096 + nq0 + lr))*32 + 8*lg);

    f32x4 po[8];
    #pragma unroll
    for (int ct = 0; ct < 8; ++ct) po[ct] = zero;
    float m_run = -1e30f, l_run = 0.f;

    const unsigned short* phb = phi_t + (size_t)b * 1024 * 32;
    const unsigned short* gb  = g + (size_t)b * 128 * 1024;
    unsigned short* pw = plds[wv];

    #pragma unroll 1
    for (int kt = 0; kt < 16; ++kt) {
        const int mb = kt * 64;
        // ---- S^T = phi * theta: 4 MFMAs. lane: q=lr, m=16mt+4lg+r
        f32x4 s[4];
        #pragma unroll
        for (int mt = 0; mt < 4; ++mt) {
            bf16x8 ap = *(const bf16x8*)(phb + (size_t)(mb + 16*mt + lr)*32 + 8*lg);
            s[mt] = __builtin_amdgcn_mfma_f32_16x16x32_bf16(ap, aq, zero, 0, 0, 0);
        }
        // ---- online softmax for row q=lr (in-lane 16 vals + 2 shfls)
        float mx = -1e30f;
        #pragma unroll
        for (int mt = 0; mt < 4; ++mt)
            #pragma unroll
            for (int r = 0; r < 4; ++r) mx = fmaxf(mx, s[mt][r]);
        mx = fmaxf(mx, __shfl_xor(mx, 16));
        mx = fmaxf(mx, __shfl_xor(mx, 32));
        float nm = fmaxf(m_run, mx);
        float sc = __expf(m_run - nm);
        float ls = 0.f;
        #pragma unroll
        for (int mt = 0; mt < 4; ++mt)
            #pragma unroll
            for (int r = 0; r < 4; ++r) {
                float p = __expf(s[mt][r] - nm);
                s[mt][r] = p; ls += p;
            }
        ls += __shfl_xor(ls, 16);
        ls += __shfl_xor(ls, 32);
        l_run = l_run * sc + ls;
        m_run = nm;
        // ---- rescale accumulators (po rows are q=4lg+r; stats live at lane q)
        float scB[4];
        #pragma unroll
        for (int r = 0; r < 4; ++r) scB[r] = __shfl(sc, 4*lg + r);
        #pragma unroll
        for (int ct = 0; ct < 8; ++ct)
            #pragma unroll
            for (int r = 0; r < 4; ++r) po[ct][r] *= scB[r];
        // ---- P -> LDS packed u32 (wave-private, no barrier)
        #pragma unroll
        for (int mt = 0; mt < 4; ++mt)
            #pragma unroll
            for (int i = 0; i < 2; ++i)
                *(unsigned*)(pw + lr*72 + 16*mt + 4*lg + 2*i) =
                    packbf2(s[mt][2*i], s[mt][2*i + 1]);
        // ---- PV: A=P[q][m] (ds_read_b128), B=g[c][m] (int4 global)
        #pragma unroll
        for (int ks = 0; ks < 2; ++ks) {
            bf16x8 pa = *(const bf16x8*)(pw + lr*72 + 32*ks + 8*lg);
            #pragma unroll
            for (int ct = 0; ct < 8; ++ct) {
                bf16x8 bgv = *(const bf16x8*)(gb + (size_t)(16*ct + lr)*1024 + mb + 32*ks + 8*lg);
                po[ct] = __builtin_amdgcn_mfma_f32_16x16x32_bf16(pa, bgv, po[ct], 0, 0, 0);
            }
        }
    }

    // ---- normalize (broadcast inv), stage, coalesced int4 write
    float invq = 1.f / l_run;
    float invB[4];
    #pragma unroll
    for (int r = 0; r < 4; ++r) invB[r] = __shfl(invq, 4*lg + r);
    unsigned short* ow = olds[wv];
    #pragma unroll
    for (int ct = 0; ct < 8; ++ct)
        #pragma unroll
        for (int r = 0; r < 4; ++r)
            ow[(4*lg + r)*136 + 16*ct + lr] = f2bfbits(po[ct][r] * invB[r]);
    #pragma unroll
    for (int i = 0; i < 4; ++i) {
        int q = 4*i + lg;
        int4 v = *(const int4*)(ow + q*136 + 8*lr);
        *(int4*)(o_pre_t + ((size_t)(b*4096 + nq0 + q))*128 + 8*lr) = v;
    }
}

// ---------------------------------------------------------------------------
// out: GEMM [256 co] x [128 c2] x [64 n/block] + gamma*o + x residual.
// ---------------------------------------------------------------------------
__global__ __launch_bounds__(256, 2) void out_kernel(
    const unsigned short* __restrict__ o_pre_t,
    const unsigned short* __restrict__ w_o_bf,
    const float* __restrict__ b_o,
    const float* __restrict__ x,
    const float* __restrict__ gamma,
    float* __restrict__ out)
{
    const int t = threadIdx.x;
    const int w = t >> 6, l = t & 63;
    const int lr = l & 15, lg = l >> 4;
    const int b   = blockIdx.x >> 6;
    const int nbv = (blockIdx.x & 63) << 6;

    f32x4 acc[4][4];
    #pragma unroll
    for (int i = 0; i < 4; ++i)
        #pragma unroll
        for (int nt = 0; nt < 4; ++nt) acc[i][nt] = (f32x4){0.f,0.f,0.f,0.f};

    #pragma unroll 1
    for (int ks = 0; ks < 4; ++ks) {
        bf16x8 aw[4], bo[4];
        #pragma unroll
        for (int i = 0; i < 4; ++i)
            aw[i] = *(const bf16x8*)(w_o_bf + (size_t)(16*(4*w+i) + lr)*128 + 32*ks + 8*lg);
        #pragma unroll
        for (int nt = 0; nt < 4; ++nt)
            bo[nt] = *(const bf16x8*)(o_pre_t + ((size_t)(b*4096 + nbv + 16*nt + lr))*128 + 32*ks + 8*lg);
        #pragma unroll
        for (int i = 0; i < 4; ++i)
            #pragma unroll
            for (int nt = 0; nt < 4; ++nt)
                acc[i][nt] = __builtin_amdgcn_mfma_f32_16x16x32_bf16(aw[i], bo[nt], acc[i][nt], 0, 0, 0);
    }

    const float gam = gamma[0];
    float bias[4][4];
    #pragma unroll
    for (int i = 0; i < 4; ++i)
        #pragma unroll
        for (int r = 0; r < 4; ++r) bias[i][r] = b_o[16*(4*w+i) + 4*lg + r];

    #pragma unroll
    for (int i = 0; i < 4; ++i)
        #pragma unroll
        for (int nt = 0; nt < 4; ++nt)
            #pragma unroll
            for (int r = 0; r < 4; ++r) {
                int co = 16*(4*w+i) + 4*lg + r;
                int n  = nbv + 16*nt + lr;
                size_t off = ((size_t)(b*256 + co)) * 4096 + n;
                out[off] = gam * (acc[i][nt][r] + bias[i][r]) + x[off];
            }
}

// ---------------------------------------------------------------------------
extern "C" void kernel_launch(void* const* d_in, const int* in_sizes, int n_in,
                              void* d_out, int out_size, void* d_ws, size_t ws_size,
                              hipStream_t stream)
{
    const float* x       = (const float*)d_in[0];
    const float* w_theta = (const float*)d_in[1];
    const float* b_theta = (const float*)d_in[2];
    const float* w_phi   = (const float*)d_in[3];
    const float* b_phi   = (const float*)d_in[4];
    const float* w_g     = (const float*)d_in[5];
    const float* b_g     = (const float*)d_in[6];
    const float* w_o     = (const float*)d_in[7];
    const float* b_o     = (const float*)d_in[8];
    const float* gamma   = (const float*)d_in[9];
    float* outp = (float*)d_out;

    char* ws = (char*)d_ws;
    unsigned short* w_all   = (unsigned short*)ws;                  // 96 KB
    unsigned short* w_o_bf  = (unsigned short*)(ws + 98304);        // 64 KB
    float*          b_all   = (float*)(ws + 163840);                // 768 B
    unsigned short* x_t     = (unsigned short*)(ws + (1u << 20));   // 32 MB [B][4096][256]
    unsigned short* o_pre_t = (unsigned short*)(ws + (1u << 20));   // 16 MB (aliases x_t; lifetimes disjoint)
    unsigned short* theta_t = (unsigned short*)(ws + (33u << 20));  // 4 MB [B][4096][32]
    unsigned short* phi_t   = (unsigned short*)(ws + (37u << 20));  // 1 MB [B][1024][32]
    unsigned short* g       = (unsigned short*)(ws + (38u << 20));  // 4 MB [B][128][1024]

    prep_kernel<<<321, 256, 0, stream>>>(w_theta, b_theta, w_phi, b_phi,
                                         w_g, b_g, w_o, w_all, w_o_bf, b_all);
    xt_kernel<<<BB * 256, 256, 0, stream>>>(x, x_t);
    proj_kernel<<<BB * 32, 256, 0, stream>>>(x_t, w_all, b_all, theta_t, phi_t, g);
    attn_kernel<<<BB * 64, 256, 0, stream>>>(theta_t, phi_t, g, o_pre_t);
    out_kernel<<<BB * 64, 256, 0, stream>>>(o_pre_t, w_o_bf, b_o, x, gamma, outp);
}

// Round 5
// 262.050 us; speedup vs baseline: 1.2026x; 1.2026x over previous
//
#include <hip/hip_runtime.h>
#include <hip/hip_bf16.h>

#define BB 16

typedef __attribute__((ext_vector_type(8))) short bf16x8;
typedef __attribute__((ext_vector_type(4))) float f32x4;

__device__ __forceinline__ unsigned short f2bfbits(float f) {
    union { float f; unsigned u; } v; v.f = f;
    unsigned r = v.u + 0x7fffu + ((v.u >> 16) & 1u);   // RNE
    return (unsigned short)(r >> 16);
}
__device__ __forceinline__ float bfraw(unsigned short u) {
    union { unsigned u; float f; } v; v.u = ((unsigned)u) << 16; return v.f;
}
__device__ __forceinline__ unsigned packbf2(float lo, float hi) {
    return (unsigned)f2bfbits(lo) | ((unsigned)f2bfbits(hi) << 16);
}

// ---------------------------------------------------------------------------
// prep: fp32 params -> bf16 ws copies.
// ---------------------------------------------------------------------------
__global__ void prep_kernel(
    const float* __restrict__ wt, const float* __restrict__ bt,
    const float* __restrict__ wp, const float* __restrict__ bp,
    const float* __restrict__ wg, const float* __restrict__ bg,
    const float* __restrict__ wo,
    unsigned short* __restrict__ w_all, unsigned short* __restrict__ w_o_bf,
    float* __restrict__ b_all)
{
    int i = blockIdx.x * 256 + threadIdx.x;
    if (i < 8192)        w_all[i] = f2bfbits(wt[i]);
    else if (i < 16384)  w_all[i] = f2bfbits(wp[i - 8192]);
    else if (i < 49152)  w_all[i] = f2bfbits(wg[i - 16384]);
    else if (i < 81920)  w_o_bf[i - 49152] = f2bfbits(wo[i - 49152]);
    else if (i < 82112) {
        int r = i - 81920;
        b_all[r] = (r < 32) ? bt[r] : (r < 64) ? bp[r - 32] : bg[r - 64];
    }
}

// ---------------------------------------------------------------------------
// xT: x fp32 [B][256][4096] -> x_t bf16 [B][4096][256]. 64x64 LDS tiles.
// ---------------------------------------------------------------------------
__global__ __launch_bounds__(256) void xt_kernel(
    const float* __restrict__ x, unsigned short* __restrict__ x_t)
{
    __shared__ unsigned short lt[64 * 74];

    const int t = threadIdx.x;
    const int bid = blockIdx.x;
    const int b  = bid >> 8;
    const int p0 = ((bid >> 2) & 63) << 6;
    const int c0 = (bid & 3) << 6;

    {
        int c = t & 63, seg = t >> 6;
        const float* src = x + ((size_t)(b * 256 + c0 + c)) * 4096 + p0 + seg * 16;
        #pragma unroll
        for (int j = 0; j < 4; ++j) {
            float4 v = *(const float4*)(src + 4 * j);
            unsigned* dst = (unsigned*)(lt + c * 74 + seg * 16 + 4 * j);
            dst[0] = packbf2(v.x, v.y);
            dst[1] = packbf2(v.z, v.w);
        }
    }
    __syncthreads();
    {
        int p = t >> 2, quad = t & 3;
        #pragma unroll
        for (int h = 0; h < 2; ++h) {
            union { unsigned short u[8]; int4 v; } o;
            #pragma unroll
            for (int e = 0; e < 8; ++e)
                o.u[e] = lt[(quad * 16 + h * 8 + e) * 74 + p];
            *(int4*)(x_t + ((size_t)(b * 4096 + p0 + p)) * 256 + c0 + quad * 16 + h * 8) = o.v;
        }
    }
}

// ---------------------------------------------------------------------------
// proj: [192 co] x [256 cin] x [128 pos/block] MFMA GEMM + bias + pool.
// ---------------------------------------------------------------------------
__global__ __launch_bounds__(256, 2) void proj_kernel(
    const unsigned short* __restrict__ x_t,
    const unsigned short* __restrict__ w_all,
    const float* __restrict__ b_all,
    unsigned short* __restrict__ theta_t,   // [B][4096][32]
    unsigned short* __restrict__ phi_t,     // [B][1024][32]
    unsigned short* __restrict__ g)         // [B][128][1024]
{
    __shared__ unsigned short ot[192 * 136];

    const int t = threadIdx.x;
    const int w = t >> 6;
    const int l = t & 63;
    const int lr = l & 15, lg = l >> 4;
    const int b  = blockIdx.x >> 5;
    const int pt = blockIdx.x & 31;
    const int pbase = pt << 7;
    const int mb = pt << 5;

    f32x4 acc[3][8];
    #pragma unroll
    for (int i = 0; i < 3; ++i)
        #pragma unroll
        for (int nt = 0; nt < 8; ++nt) acc[i][nt] = (f32x4){0.f,0.f,0.f,0.f};

    #pragma unroll 2
    for (int ks = 0; ks < 8; ++ks) {
        bf16x8 af[3];
        #pragma unroll
        for (int i = 0; i < 3; ++i)
            af[i] = *(const bf16x8*)(w_all + (size_t)(16*(3*w+i) + lr)*256 + 32*ks + 8*lg);
        #pragma unroll
        for (int nt = 0; nt < 8; ++nt) {
            bf16x8 bx = *(const bf16x8*)(x_t + ((size_t)(b*4096 + pbase + 16*nt + lr))*256 + 32*ks + 8*lg);
            #pragma unroll
            for (int i = 0; i < 3; ++i)
                acc[i][nt] = __builtin_amdgcn_mfma_f32_16x16x32_bf16(af[i], bx, acc[i][nt], 0, 0, 0);
        }
    }

    float bias[3][4];
    #pragma unroll
    for (int i = 0; i < 3; ++i)
        #pragma unroll
        for (int r = 0; r < 4; ++r) bias[i][r] = b_all[16*(3*w+i) + 4*lg + r];
    #pragma unroll
    for (int i = 0; i < 3; ++i)
        #pragma unroll
        for (int nt = 0; nt < 8; ++nt)
            #pragma unroll
            for (int r = 0; r < 4; ++r)
                ot[(16*(3*w+i) + 4*lg + r)*136 + 16*nt + lr] =
                    f2bfbits(acc[i][nt][r] + bias[i][r]);
    __syncthreads();

    if (t < 128) {
        int p = t;
        union { unsigned short u[32]; int4 v[4]; } th;
        #pragma unroll
        for (int c = 0; c < 32; ++c) th.u[c] = ot[c*136 + p];
        int4* dst = (int4*)(theta_t + ((size_t)(b*4096 + pbase + p)) * 32);
        #pragma unroll
        for (int q = 0; q < 4; ++q) dst[q] = th.v[q];
    }
    {
        int ww = t >> 3, c0 = (t & 7) * 4;
        union { unsigned short u[4]; int2 v; } ph;
        #pragma unroll
        for (int e = 0; e < 4; ++e) {
            int row = 32 + c0 + e;
            unsigned p01 = *(const unsigned*)&ot[row*136 + 2*ww];
            unsigned p23 = *(const unsigned*)&ot[row*136 + 64 + 2*ww];
            float m0 = fmaxf(bfraw((unsigned short)p01), bfraw((unsigned short)(p01 >> 16)));
            float m1 = fmaxf(bfraw((unsigned short)p23), bfraw((unsigned short)(p23 >> 16)));
            ph.u[e] = f2bfbits(fmaxf(m0, m1));
        }
        *(int2*)(phi_t + ((size_t)(b*1024 + mb + ww)) * 32 + c0) = ph.v;
    }
    {
        int c2 = t >> 1, w0 = (t & 1) * 16;
        int row = 64 + c2;
        union { unsigned short u[16]; int4 v[2]; } gv;
        #pragma unroll
        for (int e = 0; e < 16; ++e) {
            int ww = w0 + e;
            unsigned p01 = *(const unsigned*)&ot[row*136 + 2*ww];
            unsigned p23 = *(const unsigned*)&ot[row*136 + 64 + 2*ww];
            float m0 = fmaxf(bfraw((unsigned short)p01), bfraw((unsigned short)(p01 >> 16)));
            float m1 = fmaxf(bfraw((unsigned short)p23), bfraw((unsigned short)(p23 >> 16)));
            gv.u[e] = f2bfbits(fmaxf(m0, m1));
        }
        int4* dst = (int4*)(g + ((size_t)(b*128 + c2)) * 1024 + mb + w0);
        dst[0] = gv.v[0]; dst[1] = gv.v[1];
    }
}

// ---------------------------------------------------------------------------
// attn v3: 4 independent waves/block, 32 q per wave, 1024 keys, chunks of 64.
// Swapped QK^T; in-lane softmax; register prefetch of g (same-kt) and phi
// (next-kt) so global latency hides under QK+softmax+PV.
// ---------------------------------------------------------------------------
__global__ __launch_bounds__(256, 2) void attn_kernel(
    const unsigned short* __restrict__ theta_t,
    const unsigned short* __restrict__ phi_t,
    const unsigned short* __restrict__ g,
    unsigned short* __restrict__ o_pre_t)   // [B][4096][128]
{
    __shared__ unsigned short plds[4][32 * 72];
    __shared__ unsigned short olds[4][32 * 136];

    const int t = threadIdx.x;
    const int wv = t >> 6;
    const int l  = t & 63;
    const int lr = l & 15, lg = l >> 4;
    const int b   = blockIdx.x >> 5;
    const int nq0 = (blockIdx.x & 31) * 128 + wv * 32;

    const f32x4 zero = {0.f, 0.f, 0.f, 0.f};

    // theta B-frags (col=q), hoisted
    bf16x8 aq[2];
    #pragma unroll
    for (int qt = 0; qt < 2; ++qt)
        aq[qt] = *(const bf16x8*)(theta_t + ((size_t)(b*4096 + nq0 + 16*qt + lr))*32 + 8*lg);

    f32x4 po[2][8];
    #pragma unroll
    for (int qt = 0; qt < 2; ++qt)
        #pragma unroll
        for (int ct = 0; ct < 8; ++ct) po[qt][ct] = zero;
    float m_run[2] = {-1e30f, -1e30f}, l_run[2] = {0.f, 0.f};

    const unsigned short* phb = phi_t + (size_t)b * 1024 * 32;
    const unsigned short* gb  = g + (size_t)b * 128 * 1024;
    unsigned short* pw = plds[wv];

    // prime phi frags for kt=0 (A-frag: row=m, k contiguous)
    bf16x8 pf[4];
    #pragma unroll
    for (int mt = 0; mt < 4; ++mt)
        pf[mt] = *(const bf16x8*)(phb + (size_t)(16*mt + lr)*32 + 8*lg);

    #pragma unroll 1
    for (int kt = 0; kt < 16; ++kt) {
        const int mb = kt * 64;
        // ---- issue ALL g loads for this kt now; consumed in PV far below
        bf16x8 gv[16];
        #pragma unroll
        for (int ks = 0; ks < 2; ++ks)
            #pragma unroll
            for (int ct = 0; ct < 8; ++ct)
                gv[ks*8 + ct] = *(const bf16x8*)(gb + (size_t)(16*ct + lr)*1024 + mb + 32*ks + 8*lg);

        // ---- QK^T (swapped): s[qt][mt], lane holds q=lr, m=16mt+4lg+r
        f32x4 s[2][4];
        #pragma unroll
        for (int mt = 0; mt < 4; ++mt) {
            s[0][mt] = __builtin_amdgcn_mfma_f32_16x16x32_bf16(pf[mt], aq[0], zero, 0, 0, 0);
            s[1][mt] = __builtin_amdgcn_mfma_f32_16x16x32_bf16(pf[mt], aq[1], zero, 0, 0, 0);
        }
        // ---- prefetch next kt's phi frags (WAR on pf is just ordering)
        {
            const int mbn = (kt < 15) ? mb + 64 : mb;
            #pragma unroll
            for (int mt = 0; mt < 4; ++mt)
                pf[mt] = *(const bf16x8*)(phb + (size_t)(mbn + 16*mt + lr)*32 + 8*lg);
        }

        // ---- online softmax per qt (in-lane 16 vals + 2 shfls)
        float scv[2];
        #pragma unroll
        for (int qt = 0; qt < 2; ++qt) {
            float mx = -1e30f;
            #pragma unroll
            for (int mt = 0; mt < 4; ++mt)
                #pragma unroll
                for (int r = 0; r < 4; ++r) mx = fmaxf(mx, s[qt][mt][r]);
            mx = fmaxf(mx, __shfl_xor(mx, 16));
            mx = fmaxf(mx, __shfl_xor(mx, 32));
            float nm = fmaxf(m_run[qt], mx);
            float sc = __expf(m_run[qt] - nm);
            float ls = 0.f;
            #pragma unroll
            for (int mt = 0; mt < 4; ++mt)
                #pragma unroll
                for (int r = 0; r < 4; ++r) {
                    float p = __expf(s[qt][mt][r] - nm);
                    s[qt][mt][r] = p; ls += p;
                }
            ls += __shfl_xor(ls, 16);
            ls += __shfl_xor(ls, 32);
            l_run[qt] = l_run[qt] * sc + ls;
            m_run[qt] = nm;
            scv[qt] = sc;
        }
        // ---- rescale accumulators (po rows q=16qt+4lg+r; stats at lane 4lg+r)
        #pragma unroll
        for (int qt = 0; qt < 2; ++qt) {
            float scB[4];
            #pragma unroll
            for (int r = 0; r < 4; ++r) scB[r] = __shfl(scv[qt], 4*lg + r);
            #pragma unroll
            for (int ct = 0; ct < 8; ++ct)
                #pragma unroll
                for (int r = 0; r < 4; ++r) po[qt][ct][r] *= scB[r];
        }
        // ---- P -> LDS packed u32 (wave-private)
        #pragma unroll
        for (int qt = 0; qt < 2; ++qt)
            #pragma unroll
            for (int mt = 0; mt < 4; ++mt)
                #pragma unroll
                for (int i = 0; i < 2; ++i)
                    *(unsigned*)(pw + (16*qt + lr)*72 + 16*mt + 4*lg + 2*i) =
                        packbf2(s[qt][mt][2*i], s[qt][mt][2*i + 1]);
        // ---- PV: A=P rows (ds_read_b128), B=g frags (already in flight)
        #pragma unroll
        for (int ks = 0; ks < 2; ++ks) {
            bf16x8 pa0 = *(const bf16x8*)(pw + (size_t)lr*72 + 32*ks + 8*lg);
            bf16x8 pa1 = *(const bf16x8*)(pw + (size_t)(16 + lr)*72 + 32*ks + 8*lg);
            #pragma unroll
            for (int ct = 0; ct < 8; ++ct) {
                po[0][ct] = __builtin_amdgcn_mfma_f32_16x16x32_bf16(pa0, gv[ks*8+ct], po[0][ct], 0, 0, 0);
                po[1][ct] = __builtin_amdgcn_mfma_f32_16x16x32_bf16(pa1, gv[ks*8+ct], po[1][ct], 0, 0, 0);
            }
        }
    }

    // ---- normalize, stage, coalesced int4 write
    float invB[2][4];
    #pragma unroll
    for (int qt = 0; qt < 2; ++qt) {
        float invq = 1.f / l_run[qt];
        #pragma unroll
        for (int r = 0; r < 4; ++r) invB[qt][r] = __shfl(invq, 4*lg + r);
    }
    unsigned short* ow = olds[wv];
    #pragma unroll
    for (int qt = 0; qt < 2; ++qt)
        #pragma unroll
        for (int ct = 0; ct < 8; ++ct)
            #pragma unroll
            for (int r = 0; r < 4; ++r)
                ow[(16*qt + 4*lg + r)*136 + 16*ct + lr] = f2bfbits(po[qt][ct][r] * invB[qt][r]);
    #pragma unroll
    for (int i = 0; i < 8; ++i) {
        int q = 4*i + lg;
        int4 v = *(const int4*)(ow + q*136 + 8*lr);
        *(int4*)(o_pre_t + ((size_t)(b*4096 + nq0 + q))*128 + 8*lr) = v;
    }
}

// ---------------------------------------------------------------------------
// out: GEMM [256 co] x [128 c2] x [64 n/block] + gamma*o + x residual.
// ---------------------------------------------------------------------------
__global__ __launch_bounds__(256, 2) void out_kernel(
    const unsigned short* __restrict__ o_pre_t,
    const unsigned short* __restrict__ w_o_bf,
    const float* __restrict__ b_o,
    const float* __restrict__ x,
    const float* __restrict__ gamma,
    float* __restrict__ out)
{
    const int t = threadIdx.x;
    const int w = t >> 6, l = t & 63;
    const int lr = l & 15, lg = l >> 4;
    const int b   = blockIdx.x >> 6;
    const int nbv = (blockIdx.x & 63) << 6;

    f32x4 acc[4][4];
    #pragma unroll
    for (int i = 0; i < 4; ++i)
        #pragma unroll
        for (int nt = 0; nt < 4; ++nt) acc[i][nt] = (f32x4){0.f,0.f,0.f,0.f};

    #pragma unroll 2
    for (int ks = 0; ks < 4; ++ks) {
        bf16x8 aw[4], bo[4];
        #pragma unroll
        for (int i = 0; i < 4; ++i)
            aw[i] = *(const bf16x8*)(w_o_bf + (size_t)(16*(4*w+i) + lr)*128 + 32*ks + 8*lg);
        #pragma unroll
        for (int nt = 0; nt < 4; ++nt)
            bo[nt] = *(const bf16x8*)(o_pre_t + ((size_t)(b*4096 + nbv + 16*nt + lr))*128 + 32*ks + 8*lg);
        #pragma unroll
        for (int i = 0; i < 4; ++i)
            #pragma unroll
            for (int nt = 0; nt < 4; ++nt)
                acc[i][nt] = __builtin_amdgcn_mfma_f32_16x16x32_bf16(aw[i], bo[nt], acc[i][nt], 0, 0, 0);
    }

    const float gam = gamma[0];
    float bias[4][4];
    #pragma unroll
    for (int i = 0; i < 4; ++i)
        #pragma unroll
        for (int r = 0; r < 4; ++r) bias[i][r] = b_o[16*(4*w+i) + 4*lg + r];

    #pragma unroll
    for (int i = 0; i < 4; ++i)
        #pragma unroll
        for (int nt = 0; nt < 4; ++nt)
            #pragma unroll
            for (int r = 0; r < 4; ++r) {
                int co = 16*(4*w+i) + 4*lg + r;
                int n  = nbv + 16*nt + lr;
                size_t off = ((size_t)(b*256 + co)) * 4096 + n;
                out[off] = gam * (acc[i][nt][r] + bias[i][r]) + x[off];
            }
}

// ---------------------------------------------------------------------------
extern "C" void kernel_launch(void* const* d_in, const int* in_sizes, int n_in,
                              void* d_out, int out_size, void* d_ws, size_t ws_size,
                              hipStream_t stream)
{
    const float* x       = (const float*)d_in[0];
    const float* w_theta = (const float*)d_in[1];
    const float* b_theta = (const float*)d_in[2];
    const float* w_phi   = (const float*)d_in[3];
    const float* b_phi   = (const float*)d_in[4];
    const float* w_g     = (const float*)d_in[5];
    const float* b_g     = (const float*)d_in[6];
    const float* w_o     = (const float*)d_in[7];
    const float* b_o     = (const float*)d_in[8];
    const float* gamma   = (const float*)d_in[9];
    float* outp = (float*)d_out;

    char* ws = (char*)d_ws;
    unsigned short* w_all   = (unsigned short*)ws;                  // 96 KB
    unsigned short* w_o_bf  = (unsigned short*)(ws + 98304);        // 64 KB
    float*          b_all   = (float*)(ws + 163840);                // 768 B
    unsigned short* x_t     = (unsigned short*)(ws + (1u << 20));   // 32 MB [B][4096][256]
    unsigned short* o_pre_t = (unsigned short*)(ws + (1u << 20));   // 16 MB (aliases x_t)
    unsigned short* theta_t = (unsigned short*)(ws + (33u << 20));  // 4 MB
    unsigned short* phi_t   = (unsigned short*)(ws + (37u << 20));  // 1 MB
    unsigned short* g       = (unsigned short*)(ws + (38u << 20));  // 4 MB

    prep_kernel<<<321, 256, 0, stream>>>(w_theta, b_theta, w_phi, b_phi,
                                         w_g, b_g, w_o, w_all, w_o_bf, b_all);
    xt_kernel<<<BB * 256, 256, 0, stream>>>(x, x_t);
    proj_kernel<<<BB * 32, 256, 0, stream>>>(x_t, w_all, b_all, theta_t, phi_t, g);
    attn_kernel<<<BB * 32, 256, 0, stream>>>(theta_t, phi_t, g, o_pre_t);
    out_kernel<<<BB * 64, 256, 0, stream>>>(o_pre_t, w_o_bf, b_o, x, gamma, outp);
}